// Round 8
// baseline (148.717 us; speedup 1.0000x reference)
//
#include <hip/hip_runtime.h>
#include <hip/hip_bf16.h>
#include <cstddef>

#define NBATCH 16384
#define NNB 32
#define DD 128
#define NH 4
#define NHD 512   // NH * DD

typedef __attribute__((ext_vector_type(8))) short short8v;  // 8 bf16
typedef __attribute__((ext_vector_type(4))) float f32x4;

// bf16 pack helpers (round-to-nearest-even)
__device__ __forceinline__ unsigned f2bf1(float f) {
  unsigned u = __float_as_uint(f);
  return (u + 0x7FFFu + ((u >> 16) & 1u)) >> 16;
}
__device__ __forceinline__ unsigned pack2bf(float lo, float hi) {
  return f2bf1(lo) | (f2bf1(hi) << 16);
}
__device__ __forceinline__ float bflo(unsigned u) { return __uint_as_float(u << 16); }
__device__ __forceinline__ float bfhi(unsigned u) { return __uint_as_float(u & 0xFFFF0000u); }

// ---------------------------------------------------------------------------
// K0: AA[i][h*128+d] = sum_r Wq[h][r][i]*Wk[h][r][d]                  (fp32)
//     CCf = 0.25 * Wo@Wv, bf16 in MFMA B-fragment order (R7-verified):
//       o = t*16 + (l&15), k = s*32 + (l>>4)*8 + e
//       ushort idx = ((t*16+s)*64 + l)*8 + e
// ---------------------------------------------------------------------------
__global__ __launch_bounds__(256) void precompute_kernel(
    const float* __restrict__ Wq, const float* __restrict__ Wk,
    const float* __restrict__ Wv, const float* __restrict__ Wo,
    float* __restrict__ AA, unsigned short* __restrict__ CCf) {
  int e = blockIdx.x * 256 + threadIdx.x;   // 0..65535
  if (blockIdx.y == 0) {
    int i = e >> 9;            // 0..127
    int hd = e & 511;
    int h = hd >> 7, d = hd & 127;
    const float* wq = Wq + h * 16384;
    const float* wk = Wk + h * 16384;
    float acc = 0.f;
    #pragma unroll 8
    for (int r = 0; r < 128; ++r) acc += wq[r * 128 + i] * wk[r * 128 + d];
    AA[e] = acc;
  } else {
    int k = e >> 7;            // 0..511  (k = h*128 + i)
    int o = e & 127;
    int h = k >> 7, i = k & 127;
    const float* wv = Wv + h * 16384;
    float acc = 0.f;
    #pragma unroll 8
    for (int d = 0; d < 128; ++d) acc += Wo[o * 128 + d] * wv[d * 128 + i];
    int t = o >> 4, s = k >> 5, g = (k >> 3) & 3, eo = k & 7;
    int lane = (o & 15) + 16 * g;
    size_t idx = ((size_t)(t * 16 + s) * 64 + lane) * 8 + eo;
    CCf[idx] = (unsigned short)f2bf1(0.25f * acc);
  }
}

// ---------------------------------------------------------------------------
// K1: G[b][hd] = sum_i x[b][i]*AA[i][hd]  (standalone fp32 VALU GEMM)
// ---------------------------------------------------------------------------
__global__ __launch_bounds__(512) void gemm1_kernel(
    const float* __restrict__ x, const float* __restrict__ AA,
    float* __restrict__ G) {
  __shared__ __align__(16) float x_lds[16][DD];   // 8 KB
  const int t = threadIdx.x;
  const size_t b0 = (size_t)blockIdx.x * 16;
  {
    float4 v = ((const float4*)(x + b0 * DD))[t];
    ((float4*)x_lds)[t] = v;
  }
  __syncthreads();
  const int hdq = t & 127;   // hd = 4*hdq
  const int bq  = t >> 7;    // batches 4*bq .. 4*bq+3
  const float4* AA4 = (const float4*)AA;   // [128][128] float4
  float4 acc[4];
  #pragma unroll
  for (int j = 0; j < 4; ++j) acc[j] = make_float4(0.f, 0.f, 0.f, 0.f);
  #pragma unroll 2
  for (int i4 = 0; i4 < 128; i4 += 4) {
    float4 a0 = AA4[(i4 + 0) * 128 + hdq];
    float4 a1 = AA4[(i4 + 1) * 128 + hdq];
    float4 a2 = AA4[(i4 + 2) * 128 + hdq];
    float4 a3 = AA4[(i4 + 3) * 128 + hdq];
    #pragma unroll
    for (int j = 0; j < 4; ++j) {
      float4 xv = *(const float4*)&x_lds[4 * bq + j][i4];  // wave-uniform
      acc[j].x += xv.x * a0.x + xv.y * a1.x + xv.z * a2.x + xv.w * a3.x;
      acc[j].y += xv.x * a0.y + xv.y * a1.y + xv.z * a2.y + xv.w * a3.y;
      acc[j].z += xv.x * a0.z + xv.y * a1.z + xv.z * a2.z + xv.w * a3.z;
      acc[j].w += xv.x * a0.w + xv.y * a1.w + xv.z * a2.w + xv.w * a3.w;
    }
  }
  #pragma unroll
  for (int j = 0; j < 4; ++j)
    *(float4*)(G + (b0 + 4 * bq + j) * NHD + 4 * hdq) = acc[j];
}

// ---------------------------------------------------------------------------
// K2: attention + out-GEMM. 256 thr / 8 batches / block.
//  - stage nb slab coalesced fp32->bf16 into LDS (rows padded to 136)
//  - logits via MFMA: A = nb16 rows, B = g (hi+lo bf16 split from fp32 G)
//  - softmax in C-layout (2 shuffles), attn bf16 to LDS
//  - PV on VALU from LDS (lane owns 2 columns, stride-1)
//  - out = ws@CCf via MFMA (R7-verified layout), bias+leaky fused
// ---------------------------------------------------------------------------
__global__ __launch_bounds__(256) void attn_kernel(
    const float* __restrict__ nb, const float* __restrict__ G,
    const unsigned short* __restrict__ CCf, const float* __restrict__ bo,
    float* __restrict__ out) {

  __shared__ __align__(16) unsigned short nb16[8][NNB][136];  // 69632 B
  __shared__ __align__(16) unsigned ws16[8][260];             // 8320 B (520 bf16/row)
  __shared__ __align__(16) unsigned short at16[8][NNB][4];    // 2048 B

  const int t = threadIdx.x;
  const size_t B0 = (size_t)blockIdx.x * 8;

  // ---- stage: 8 batches x 16 KB, coalesced, fp32 -> bf16
  {
    const float4* src = (const float4*)(nb + B0 * (NNB * DD));
    #pragma unroll 4
    for (int i = 0; i < 32; ++i) {
      int flat = i * 256 + t;        // 0..8191 float4s
      float4 f = src[flat];
      int b = flat >> 10, rem = flat & 1023;
      int n = rem >> 5, c4 = rem & 31;
      unsigned* dst = (unsigned*)&nb16[b][n][c4 * 4];
      dst[0] = pack2bf(f.x, f.y);
      dst[1] = pack2bf(f.z, f.w);
    }
  }
  __syncthreads();

  // ---- per-wave attention: wave owns 2 batches
  {
    const int wv = t >> 6, l = t & 63;
    const int hm = l & 15;    // A-row within tile / B-col (head) — dual role
    const int kg = l >> 4;    // k-group
    #pragma unroll 1
    for (int c = 0; c < 2; ++c) {
      const int b = 2 * wv + c;
      // logits MFMA: C[n][h] over 2 m-tiles (n 0-15, 16-31), K=128 (4 ks)
      f32x4 acc0 = {0.f, 0.f, 0.f, 0.f}, acc1 = {0.f, 0.f, 0.f, 0.f};
      const float* gp = G + (B0 + b) * NHD + hm * DD + kg * 8;
      const char* nbb = (const char*)&nb16[b][0][0];
      #pragma unroll
      for (int ks = 0; ks < 4; ++ks) {
        float4 ga = *(const float4*)(gp + ks * 32);
        float4 gb = *(const float4*)(gp + ks * 32 + 4);
        // split g into hi + lo (both bf16) -> g contributes ~no error
        unsigned h0 = f2bf1(ga.x), h1 = f2bf1(ga.y), h2 = f2bf1(ga.z), h3 = f2bf1(ga.w);
        unsigned h4 = f2bf1(gb.x), h5 = f2bf1(gb.y), h6 = f2bf1(gb.z), h7 = f2bf1(gb.w);
        float l0 = ga.x - __uint_as_float(h0 << 16);
        float l1 = ga.y - __uint_as_float(h1 << 16);
        float l2 = ga.z - __uint_as_float(h2 << 16);
        float l3 = ga.w - __uint_as_float(h3 << 16);
        float l4 = gb.x - __uint_as_float(h4 << 16);
        float l5 = gb.y - __uint_as_float(h5 << 16);
        float l6 = gb.z - __uint_as_float(h6 << 16);
        float l7 = gb.w - __uint_as_float(h7 << 16);
        union { unsigned u[4]; short8v v; } Bhi, Blo;
        Bhi.u[0] = h0 | (h1 << 16); Bhi.u[1] = h2 | (h3 << 16);
        Bhi.u[2] = h4 | (h5 << 16); Bhi.u[3] = h6 | (h7 << 16);
        Blo.u[0] = pack2bf(l0, l1); Blo.u[1] = pack2bf(l2, l3);
        Blo.u[2] = pack2bf(l4, l5); Blo.u[3] = pack2bf(l6, l7);
        union { uint4 u; short8v v; } A0, A1;
        A0.u = *(const uint4*)(nbb + hm * 272 + ks * 64 + kg * 16);
        A1.u = *(const uint4*)(nbb + (16 + hm) * 272 + ks * 64 + kg * 16);
        acc0 = __builtin_amdgcn_mfma_f32_16x16x32_bf16(A0.v, Bhi.v, acc0, 0, 0, 0);
        acc0 = __builtin_amdgcn_mfma_f32_16x16x32_bf16(A0.v, Blo.v, acc0, 0, 0, 0);
        acc1 = __builtin_amdgcn_mfma_f32_16x16x32_bf16(A1.v, Bhi.v, acc1, 0, 0, 0);
        acc1 = __builtin_amdgcn_mfma_f32_16x16x32_bf16(A1.v, Blo.v, acc1, 0, 0, 0);
      }
      // softmax: lane holds logits for h=hm (cols>=4 garbage), n = kg*4+r (+16)
      float m = fmaxf(fmaxf(fmaxf(acc0[0], acc0[1]), fmaxf(acc0[2], acc0[3])),
                      fmaxf(fmaxf(acc1[0], acc1[1]), fmaxf(acc1[2], acc1[3])));
      m = fmaxf(m, __shfl_xor(m, 16));
      m = fmaxf(m, __shfl_xor(m, 32));
      float e0[4], e1[4], s = 0.f;
      #pragma unroll
      for (int r = 0; r < 4; ++r) {
        e0[r] = __expf(acc0[r] - m); s += e0[r];
        e1[r] = __expf(acc1[r] - m); s += e1[r];
      }
      s += __shfl_xor(s, 16);
      s += __shfl_xor(s, 32);
      float inv = 1.0f / s;
      if (hm < 4) {
        #pragma unroll
        for (int r = 0; r < 4; ++r) {
          at16[b][kg * 4 + r][hm]      = (unsigned short)f2bf1(e0[r] * inv);
          at16[b][16 + kg * 4 + r][hm] = (unsigned short)f2bf1(e1[r] * inv);
        }
      }
      // PV on VALU: lane owns cols d = 2l, 2l+1 (stride-1, conflict-free)
      float w00 = 0.f, w01 = 0.f, w10 = 0.f, w11 = 0.f;
      float w20 = 0.f, w21 = 0.f, w30 = 0.f, w31 = 0.f;
      #pragma unroll 8
      for (int n = 0; n < NNB; ++n) {
        unsigned u = *(const unsigned*)(nbb + n * 272 + (l << 2));
        float f0 = bflo(u), f1 = bfhi(u);
        uint2 au = *(const uint2*)&at16[b][n][0];   // uniform broadcast
        float a0 = bflo(au.x), a1 = bfhi(au.x);
        float a2 = bflo(au.y), a3 = bfhi(au.y);
        w00 += a0 * f0; w01 += a0 * f1;
        w10 += a1 * f0; w11 += a1 * f1;
        w20 += a2 * f0; w21 += a2 * f1;
        w30 += a3 * f0; w31 += a3 * f1;
      }
      // ws row: k = h*128 + d, uint idx = h*64 + l
      ws16[b][0 * 64 + l] = pack2bf(w00, w01);
      ws16[b][1 * 64 + l] = pack2bf(w10, w11);
      ws16[b][2 * 64 + l] = pack2bf(w20, w21);
      ws16[b][3 * 64 + l] = pack2bf(w30, w31);
    }
  }
  __syncthreads();

  // ---- out-GEMM: OUT[8,128] = WS[8,512] @ CC[512,128] via MFMA
  // wave w owns o-tiles {2w, 2w+1}; A rows duplicated (m&7) to avoid OOB.
  {
    const int w = t >> 6, l = t & 63;
    const int m = l & 15, kg = l >> 4;
    const int mb = m & 7;
    f32x4 accA = {0.f, 0.f, 0.f, 0.f}, accB = {0.f, 0.f, 0.f, 0.f};
    const uint4* Bp0 = (const uint4*)CCf + (size_t)(2 * w) * 16 * 64 + l;
    const uint4* Bp1 = (const uint4*)CCf + (size_t)(2 * w + 1) * 16 * 64 + l;
    #pragma unroll
    for (int s = 0; s < 16; ++s) {
      union { uint4 u; short8v v; } A, B0, B1;
      A.u = *(const uint4*)&ws16[mb][s * 16 + kg * 4];
      B0.u = Bp0[(size_t)s * 64];
      B1.u = Bp1[(size_t)s * 64];
      accA = __builtin_amdgcn_mfma_f32_16x16x32_bf16(A.v, B0.v, accA, 0, 0, 0);
      accB = __builtin_amdgcn_mfma_f32_16x16x32_bf16(A.v, B1.v, accB, 0, 0, 0);
    }
    const int o0 = 2 * w * 16 + m, o1 = o0 + 16;
    float bias0 = bo[o0], bias1 = bo[o1];
    #pragma unroll
    for (int r = 0; r < 4; ++r) {
      int bat = kg * 4 + r;
      if (bat < 8) {
        float v0 = accA[r] + bias0; v0 = v0 > 0.f ? v0 : 0.01f * v0;
        float v1 = accB[r] + bias1; v1 = v1 > 0.f ? v1 : 0.01f * v1;
        out[(B0 + bat) * DD + o0] = v0;
        out[(B0 + bat) * DD + o1] = v1;
      }
    }
  }
}

// ---------------------------------------------------------------------------
extern "C" void kernel_launch(void* const* d_in, const int* in_sizes, int n_in,
                              void* d_out, int out_size, void* d_ws, size_t ws_size,
                              hipStream_t stream) {
  const float* x  = (const float*)d_in[0];
  const float* nb = (const float*)d_in[1];
  const float* Wq = (const float*)d_in[2];
  const float* Wk = (const float*)d_in[3];
  const float* Wv = (const float*)d_in[4];
  const float* Wo = (const float*)d_in[5];
  const float* bo = (const float*)d_in[6];
  float* out = (float*)d_out;

  float* ws = (float*)d_ws;
  float* AA = ws;                                        // [128][512] fp32, 256 KB
  unsigned short* CCf = (unsigned short*)(ws + 65536);   // frag bf16, 128 KB
  float* G = ws + 65536 + 32768;                         // [16384][512] fp32 (+2K slack)

  precompute_kernel<<<dim3(256, 2), 256, 0, stream>>>(Wq, Wk, Wv, Wo, AA, CCf);
  gemm1_kernel<<<dim3(NBATCH / 16), 512, 0, stream>>>(x, AA, G);
  attn_kernel<<<dim3(NBATCH / 8), 256, 0, stream>>>(nb, G, CCf, bo, out);
}

// Round 9
// 128.027 us; speedup vs baseline: 1.1616x; 1.1616x over previous
//
#include <hip/hip_runtime.h>
#include <hip/hip_bf16.h>
#include <cstddef>

#define NBATCH 16384
#define NNB 32
#define DD 128
#define NH 4
#define NHD 512   // NH * DD
#define NT 512    // threads per block (attn kernel)
#define BPB 8     // batches per block (attn kernel)

typedef __attribute__((ext_vector_type(8))) short short8v;  // 8 bf16
typedef __attribute__((ext_vector_type(4))) float f32x4;

// bf16 pack helpers (round-to-nearest-even)
__device__ __forceinline__ unsigned f2bf1(float f) {
  unsigned u = __float_as_uint(f);
  return (u + 0x7FFFu + ((u >> 16) & 1u)) >> 16;
}
__device__ __forceinline__ unsigned pack2bf(float lo, float hi) {
  return f2bf1(lo) | (f2bf1(hi) << 16);
}
__device__ __forceinline__ float bflo(unsigned u) { return __uint_as_float(u << 16); }
__device__ __forceinline__ float bfhi(unsigned u) { return __uint_as_float(u & 0xFFFF0000u); }

// ---------------------------------------------------------------------------
// K0: AA[i][h*128+d] = sum_r Wq[h][r][i]*Wk[h][r][d]                  (fp32)
//     CCf = 0.25 * Wo@Wv, bf16 in MFMA B-fragment order (R7-verified):
//       o = t*16 + (l&15), k = s*32 + (l>>4)*8 + e
//       ushort idx = ((t*16+s)*64 + l)*8 + e
// ---------------------------------------------------------------------------
__global__ __launch_bounds__(256) void precompute_kernel(
    const float* __restrict__ Wq, const float* __restrict__ Wk,
    const float* __restrict__ Wv, const float* __restrict__ Wo,
    float* __restrict__ AA, unsigned short* __restrict__ CCf) {
  int e = blockIdx.x * 256 + threadIdx.x;   // 0..65535
  if (blockIdx.y == 0) {
    int i = e >> 9;            // 0..127
    int hd = e & 511;
    int h = hd >> 7, d = hd & 127;
    const float* wq = Wq + h * 16384;
    const float* wk = Wk + h * 16384;
    float acc = 0.f;
    #pragma unroll 8
    for (int r = 0; r < 128; ++r) acc += wq[r * 128 + i] * wk[r * 128 + d];
    AA[e] = acc;
  } else {
    int k = e >> 7;            // 0..511  (k = h*128 + i)
    int o = e & 127;
    int h = k >> 7, i = k & 127;
    const float* wv = Wv + h * 16384;
    float acc = 0.f;
    #pragma unroll 8
    for (int d = 0; d < 128; ++d) acc += Wo[o * 128 + d] * wv[d * 128 + i];
    int t = o >> 4, s = k >> 5, g = (k >> 3) & 3, eo = k & 7;
    int lane = (o & 15) + 16 * g;
    size_t idx = ((size_t)(t * 16 + s) * 64 + lane) * 8 + eo;
    CCf[idx] = (unsigned short)f2bf1(0.25f * acc);
  }
}

// ---------------------------------------------------------------------------
// K1: G[b][hd] = sum_i x[b][i]*AA[i][hd]  (fp32 VALU GEMM, known-good)
// ---------------------------------------------------------------------------
__global__ __launch_bounds__(512) void gemm1_kernel(
    const float* __restrict__ x, const float* __restrict__ AA,
    float* __restrict__ G) {
  __shared__ __align__(16) float x_lds[16][DD];   // 8 KB
  const int t = threadIdx.x;
  const size_t b0 = (size_t)blockIdx.x * 16;
  {
    float4 v = ((const float4*)(x + b0 * DD))[t];
    ((float4*)x_lds)[t] = v;
  }
  __syncthreads();
  const int hdq = t & 127;   // hd = 4*hdq
  const int bq  = t >> 7;    // batches 4*bq .. 4*bq+3
  const float4* AA4 = (const float4*)AA;   // [128][128] float4
  float4 acc[4];
  #pragma unroll
  for (int j = 0; j < 4; ++j) acc[j] = make_float4(0.f, 0.f, 0.f, 0.f);
  #pragma unroll 2
  for (int i4 = 0; i4 < 128; i4 += 4) {
    float4 a0 = AA4[(i4 + 0) * 128 + hdq];
    float4 a1 = AA4[(i4 + 1) * 128 + hdq];
    float4 a2 = AA4[(i4 + 2) * 128 + hdq];
    float4 a3 = AA4[(i4 + 3) * 128 + hdq];
    #pragma unroll
    for (int j = 0; j < 4; ++j) {
      float4 xv = *(const float4*)&x_lds[4 * bq + j][i4];  // wave-uniform
      acc[j].x += xv.x * a0.x + xv.y * a1.x + xv.z * a2.x + xv.w * a3.x;
      acc[j].y += xv.x * a0.y + xv.y * a1.y + xv.z * a2.y + xv.w * a3.y;
      acc[j].z += xv.x * a0.z + xv.y * a1.z + xv.z * a2.z + xv.w * a3.z;
      acc[j].w += xv.x * a0.w + xv.y * a1.w + xv.z * a2.w + xv.w * a3.w;
    }
  }
  #pragma unroll
  for (int j = 0; j < 4; ++j)
    *(float4*)(G + (b0 + 4 * bq + j) * NHD + 4 * hdq) = acc[j];
}

// ---------------------------------------------------------------------------
// K2: attention + out-GEMM. 512 thr / 8 batches / block, wave-per-batch.
// LDS 80000 B -> 2 blocks/CU = 16 waves/CU (R8 had 8 -> latency-bound).
//  - G loads issued pre-staging, B-frags built pre-barrier (latency hidden)
//  - nb staged coalesced fp32->bf16 (rows padded to 136 ushorts)
//  - logits MFMA (A = nb16 rows, B = g hi+lo split; cols 4..15 duplicate h&3)
//  - softmax in C-layout (2 shuffles), attn bf16 to LDS (wave-local, no barrier)
//  - PV on VALU from LDS (lane owns 2 cols, stride-1)
//  - out = ws@CCf via MFMA (R7-verified layout), bias+leaky fused
// ---------------------------------------------------------------------------
__global__ __launch_bounds__(NT) void attn_kernel(
    const float* __restrict__ nb, const float* __restrict__ G,
    const unsigned short* __restrict__ CCf, const float* __restrict__ bo,
    float* __restrict__ out) {

  __shared__ __align__(16) unsigned short nb16[BPB][NNB][136];  // 69632 B
  __shared__ __align__(16) unsigned ws16[BPB][260];             // 8320 B
  __shared__ __align__(16) unsigned short at16[BPB][NNB][4];    // 2048 B

  const int t = threadIdx.x;
  const size_t B0 = (size_t)blockIdx.x * BPB;
  const int wv = t >> 6, l = t & 63;
  const int hm = l & 15, kg = l >> 4;

  // ---- issue G loads FIRST (latency hides under the staging stream)
  // hm&3 clamp: cols 4..15 become duplicates of heads 0..3 (also fixes the
  // R8 OOB read at hm>=4 for the last batches)
  const float* gp = G + (B0 + wv) * NHD + (size_t)(hm & 3) * DD + kg * 8;
  float4 gA[4], gB[4];
  #pragma unroll
  for (int ks = 0; ks < 4; ++ks) {
    gA[ks] = *(const float4*)(gp + ks * 32);
    gB[ks] = *(const float4*)(gp + ks * 32 + 4);
  }

  // ---- stage: 8 batches x 16 KB, coalesced, fp32 -> bf16
  {
    const float4* src = (const float4*)(nb + B0 * (NNB * DD));
    #pragma unroll 4
    for (int i = 0; i < 16; ++i) {
      int flat = i * NT + t;        // 0..8191 float4s
      float4 f = src[flat];
      int b = flat >> 10, rem = flat & 1023;
      int n = rem >> 5, c4 = rem & 31;
      unsigned* dst = (unsigned*)&nb16[b][n][c4 * 4];
      dst[0] = pack2bf(f.x, f.y);
      dst[1] = pack2bf(f.z, f.w);
    }
  }

  // ---- build B-fragments (hi + lo bf16 split of g) pre-barrier
  short8v Bhi[4], Blo[4];
  #pragma unroll
  for (int ks = 0; ks < 4; ++ks) {
    float4 ga = gA[ks], gb = gB[ks];
    unsigned h0 = f2bf1(ga.x), h1 = f2bf1(ga.y), h2 = f2bf1(ga.z), h3 = f2bf1(ga.w);
    unsigned h4 = f2bf1(gb.x), h5 = f2bf1(gb.y), h6 = f2bf1(gb.z), h7 = f2bf1(gb.w);
    float l0 = ga.x - __uint_as_float(h0 << 16);
    float l1 = ga.y - __uint_as_float(h1 << 16);
    float l2 = ga.z - __uint_as_float(h2 << 16);
    float l3 = ga.w - __uint_as_float(h3 << 16);
    float l4 = gb.x - __uint_as_float(h4 << 16);
    float l5 = gb.y - __uint_as_float(h5 << 16);
    float l6 = gb.z - __uint_as_float(h6 << 16);
    float l7 = gb.w - __uint_as_float(h7 << 16);
    union { unsigned u[4]; short8v v; } BH, BL;
    BH.u[0] = h0 | (h1 << 16); BH.u[1] = h2 | (h3 << 16);
    BH.u[2] = h4 | (h5 << 16); BH.u[3] = h6 | (h7 << 16);
    BL.u[0] = pack2bf(l0, l1); BL.u[1] = pack2bf(l2, l3);
    BL.u[2] = pack2bf(l4, l5); BL.u[3] = pack2bf(l6, l7);
    Bhi[ks] = BH.v; Blo[ks] = BL.v;
  }
  __syncthreads();

  // ---- logits MFMA: C[n][h] over 2 m-tiles (n 0-15, 16-31), K=128
  const char* nbb = (const char*)&nb16[wv][0][0];
  f32x4 acc0 = {0.f, 0.f, 0.f, 0.f}, acc1 = {0.f, 0.f, 0.f, 0.f};
  #pragma unroll
  for (int ks = 0; ks < 4; ++ks) {
    union { uint4 u; short8v v; } A0, A1;
    A0.u = *(const uint4*)(nbb + hm * 272 + ks * 64 + kg * 16);
    A1.u = *(const uint4*)(nbb + (16 + hm) * 272 + ks * 64 + kg * 16);
    acc0 = __builtin_amdgcn_mfma_f32_16x16x32_bf16(A0.v, Bhi[ks], acc0, 0, 0, 0);
    acc0 = __builtin_amdgcn_mfma_f32_16x16x32_bf16(A0.v, Blo[ks], acc0, 0, 0, 0);
    acc1 = __builtin_amdgcn_mfma_f32_16x16x32_bf16(A1.v, Bhi[ks], acc1, 0, 0, 0);
    acc1 = __builtin_amdgcn_mfma_f32_16x16x32_bf16(A1.v, Blo[ks], acc1, 0, 0, 0);
  }
  // ---- softmax: lane holds logits for h = hm (dup for hm>=4), n = kg*4+r (+16)
  {
    float m = fmaxf(fmaxf(fmaxf(acc0[0], acc0[1]), fmaxf(acc0[2], acc0[3])),
                    fmaxf(fmaxf(acc1[0], acc1[1]), fmaxf(acc1[2], acc1[3])));
    m = fmaxf(m, __shfl_xor(m, 16));
    m = fmaxf(m, __shfl_xor(m, 32));
    float e0[4], e1[4], s = 0.f;
    #pragma unroll
    for (int r = 0; r < 4; ++r) {
      e0[r] = __expf(acc0[r] - m); s += e0[r];
      e1[r] = __expf(acc1[r] - m); s += e1[r];
    }
    s += __shfl_xor(s, 16);
    s += __shfl_xor(s, 32);
    float inv = 1.0f / s;
    if (hm < 4) {
      #pragma unroll
      for (int r = 0; r < 4; ++r) {
        at16[wv][kg * 4 + r][hm]      = (unsigned short)f2bf1(e0[r] * inv);
        at16[wv][16 + kg * 4 + r][hm] = (unsigned short)f2bf1(e1[r] * inv);
      }
    }
  }
  // ---- PV on VALU: lane owns cols d = 2l, 2l+1 (stride-1, conflict-free);
  // at16 dependency is wave-local -> no barrier needed (compiler lgkmcnt)
  {
    float w00 = 0.f, w01 = 0.f, w10 = 0.f, w11 = 0.f;
    float w20 = 0.f, w21 = 0.f, w30 = 0.f, w31 = 0.f;
    #pragma unroll 8
    for (int n = 0; n < NNB; ++n) {
      unsigned u = *(const unsigned*)(nbb + n * 272 + (l << 2));
      float f0 = bflo(u), f1 = bfhi(u);
      uint2 au = *(const uint2*)&at16[wv][n][0];   // uniform broadcast
      float a0 = bflo(au.x), a1 = bfhi(au.x);
      float a2 = bflo(au.y), a3 = bfhi(au.y);
      w00 += a0 * f0; w01 += a0 * f1;
      w10 += a1 * f0; w11 += a1 * f1;
      w20 += a2 * f0; w21 += a2 * f1;
      w30 += a3 * f0; w31 += a3 * f1;
    }
    // ws row: k = h*128 + d, uint idx = h*64 + l
    ws16[wv][0 * 64 + l] = pack2bf(w00, w01);
    ws16[wv][1 * 64 + l] = pack2bf(w10, w11);
    ws16[wv][2 * 64 + l] = pack2bf(w20, w21);
    ws16[wv][3 * 64 + l] = pack2bf(w30, w31);
  }
  __syncthreads();

  // ---- out-GEMM: OUT[8,128] = WS[8,512] @ CC[512,128] via MFMA
  // wave wv owns o-tile wv (cols wv*16..+15); A rows duplicated (m&7)
  {
    const int m = hm, mb = m & 7;
    f32x4 acc = {0.f, 0.f, 0.f, 0.f};
    const uint4* Bp = (const uint4*)CCf + (size_t)wv * 1024 + l;
    #pragma unroll
    for (int s = 0; s < 16; ++s) {
      union { uint4 u; short8v v; } A, B;
      A.u = *(const uint4*)&ws16[mb][s * 16 + kg * 4];
      B.u = Bp[(size_t)s * 64];
      acc = __builtin_amdgcn_mfma_f32_16x16x32_bf16(A.v, B.v, acc, 0, 0, 0);
    }
    const int o0 = wv * 16 + m;
    float bias0 = bo[o0];
    #pragma unroll
    for (int r = 0; r < 4; ++r) {
      int bat = kg * 4 + r;
      if (bat < 8) {
        float v0 = acc[r] + bias0;
        v0 = v0 > 0.f ? v0 : 0.01f * v0;
        out[(B0 + bat) * DD + o0] = v0;
      }
    }
  }
}

// ---------------------------------------------------------------------------
extern "C" void kernel_launch(void* const* d_in, const int* in_sizes, int n_in,
                              void* d_out, int out_size, void* d_ws, size_t ws_size,
                              hipStream_t stream) {
  const float* x  = (const float*)d_in[0];
  const float* nb = (const float*)d_in[1];
  const float* Wq = (const float*)d_in[2];
  const float* Wk = (const float*)d_in[3];
  const float* Wv = (const float*)d_in[4];
  const float* Wo = (const float*)d_in[5];
  const float* bo = (const float*)d_in[6];
  float* out = (float*)d_out;

  float* ws = (float*)d_ws;
  float* AA = ws;                                        // [128][512] fp32, 256 KB
  unsigned short* CCf = (unsigned short*)(ws + 65536);   // frag bf16, 128 KB
  float* G = ws + 65536 + 32768;                         // [16384][512] fp32

  precompute_kernel<<<dim3(256, 2), 256, 0, stream>>>(Wq, Wk, Wv, Wo, AA, CCf);
  gemm1_kernel<<<dim3(NBATCH / 16), 512, 0, stream>>>(x, AA, G);
  attn_kernel<<<dim3(NBATCH / BPB), NT, 0, stream>>>(nb, G, CCf, bo, out);
}

// Round 10
// 90.333 us; speedup vs baseline: 1.6463x; 1.4173x over previous
//
#include <hip/hip_runtime.h>
#include <hip/hip_bf16.h>
#include <cstddef>

#define NBATCH 16384
#define NNB 32
#define DD 128
#define NH 4
#define NHD 512   // NH * DD
#define NT 512    // threads per block (attn kernel)
#define BPB 8     // batches per block (attn kernel)

typedef __attribute__((ext_vector_type(8))) short short8v;  // 8 bf16
typedef __attribute__((ext_vector_type(4))) float f32x4;

// bf16 pack helpers (round-to-nearest-even)
__device__ __forceinline__ unsigned f2bf1(float f) {
  unsigned u = __float_as_uint(f);
  return (u + 0x7FFFu + ((u >> 16) & 1u)) >> 16;
}
__device__ __forceinline__ unsigned pack2bf(float lo, float hi) {
  return f2bf1(lo) | (f2bf1(hi) << 16);
}
__device__ __forceinline__ float bflo(unsigned u) { return __uint_as_float(u << 16); }
__device__ __forceinline__ float bfhi(unsigned u) { return __uint_as_float(u & 0xFFFF0000u); }

// ---------------------------------------------------------------------------
// K0: AAf (hi/lo bf16) = Wq^T Wk per head, laid out in g-GEMM B-FRAGMENT order:
//       B[k=i][n=hd]: ushort idx = ((t2*4+ks)*64 + (hd&15)+16*kg)*8 + e
//       (t2 = hd>>4, ks = i>>5, kg = (i>>3)&3, e = i&7)
//     CCf = 0.25 * Wo@Wv, bf16 in out-GEMM B-fragment order (R7-verified).
// ---------------------------------------------------------------------------
__global__ __launch_bounds__(256) void precompute_kernel(
    const float* __restrict__ Wq, const float* __restrict__ Wk,
    const float* __restrict__ Wv, const float* __restrict__ Wo,
    unsigned short* __restrict__ AAfh, unsigned short* __restrict__ AAfl,
    unsigned short* __restrict__ CCf) {
  int e = blockIdx.x * 256 + threadIdx.x;   // 0..65535
  if (blockIdx.y == 0) {
    int i = e >> 9;            // 0..127 (k of g-GEMM)
    int hd = e & 511;          // n of g-GEMM
    int h = hd >> 7, d = hd & 127;
    const float* wq = Wq + h * 16384;
    const float* wk = Wk + h * 16384;
    float acc = 0.f;
    #pragma unroll 8
    for (int r = 0; r < 128; ++r) acc += wq[r * 128 + i] * wk[r * 128 + d];
    int t2 = hd >> 4;
    int ks = i >> 5, kg = (i >> 3) & 3, eo = i & 7;
    int lane = (hd & 15) + 16 * kg;
    size_t idx = ((size_t)(t2 * 4 + ks) * 64 + lane) * 8 + eo;
    unsigned hv = f2bf1(acc);
    AAfh[idx] = (unsigned short)hv;
    AAfl[idx] = (unsigned short)f2bf1(acc - __uint_as_float(hv << 16));
  } else {
    int k = e >> 7;            // 0..511  (k = h*128 + i)
    int o = e & 127;
    int h = k >> 7, i = k & 127;
    const float* wv = Wv + h * 16384;
    float acc = 0.f;
    #pragma unroll 8
    for (int d = 0; d < 128; ++d) acc += Wo[o * 128 + d] * wv[d * 128 + i];
    int t = o >> 4, s = k >> 5, g = (k >> 3) & 3, eo = k & 7;
    int lane = (o & 15) + 16 * g;
    size_t idx = ((size_t)(t * 16 + s) * 64 + lane) * 8 + eo;
    CCf[idx] = (unsigned short)f2bf1(0.25f * acc);
  }
}

// ---------------------------------------------------------------------------
// K1: G = x@AA via bf16 MFMA with exact hi/lo 3-product split
// (xh*Ah + xl*Ah + xh*Al; dropped xl*Al ~1e-5 rel). 32 batches/block.
// Output Gf: bf16 hi/lo pairs in the logits-MFMA B-frag order:
//   hi ushort idx = b*1024 + ks*128 + h*32 + kg*8 + e   (k = ks*32+kg*8+e)
//   lo at +512.
// ---------------------------------------------------------------------------
__global__ __launch_bounds__(512) void gemm1_kernel(
    const float* __restrict__ x, const unsigned short* __restrict__ AAfh,
    const unsigned short* __restrict__ AAfl, unsigned short* __restrict__ Gf) {
  __shared__ __align__(16) float x_lds[32][132];   // ~16.9 KB (pad 132)
  const int t = threadIdx.x;
  const size_t B0 = (size_t)blockIdx.x * 32;
  {
    const float4* src = (const float4*)(x + B0 * DD);
    #pragma unroll
    for (int j = 0; j < 2; ++j) {
      int flat = j * 512 + t;          // 0..1023 float4s
      float4 f = src[flat];
      int b = flat >> 5, c4 = flat & 31;
      *(float4*)&x_lds[b][c4 * 4] = f;
    }
  }
  __syncthreads();
  const int w = t >> 6, l = t & 63;
  const int hm = l & 15, kg = l >> 4;
  const int mt = w & 1;          // m-tile (batches mt*16..+15)
  const int q = w >> 1;          // n-tile quarter (8 tiles)

  // A-frags: x rows, hi/lo split (exact)
  short8v xh[4], xl[4];
  #pragma unroll
  for (int ks = 0; ks < 4; ++ks) {
    float4 a = *(const float4*)&x_lds[mt * 16 + hm][ks * 32 + kg * 8];
    float4 b = *(const float4*)&x_lds[mt * 16 + hm][ks * 32 + kg * 8 + 4];
    unsigned h0 = f2bf1(a.x), h1 = f2bf1(a.y), h2 = f2bf1(a.z), h3 = f2bf1(a.w);
    unsigned h4 = f2bf1(b.x), h5 = f2bf1(b.y), h6 = f2bf1(b.z), h7 = f2bf1(b.w);
    union { unsigned u[4]; short8v v; } H, L;
    H.u[0] = h0 | (h1 << 16); H.u[1] = h2 | (h3 << 16);
    H.u[2] = h4 | (h5 << 16); H.u[3] = h6 | (h7 << 16);
    L.u[0] = pack2bf(a.x - __uint_as_float(h0 << 16), a.y - __uint_as_float(h1 << 16));
    L.u[1] = pack2bf(a.z - __uint_as_float(h2 << 16), a.w - __uint_as_float(h3 << 16));
    L.u[2] = pack2bf(b.x - __uint_as_float(h4 << 16), b.y - __uint_as_float(h5 << 16));
    L.u[3] = pack2bf(b.z - __uint_as_float(h6 << 16), b.w - __uint_as_float(h7 << 16));
    xh[ks] = H.v; xl[ks] = L.v;
  }

  #pragma unroll
  for (int tt = 0; tt < 8; ++tt) {
    const int t2 = q * 8 + tt;
    const uint4* Bh = (const uint4*)AAfh + (size_t)t2 * 256 + l;
    const uint4* Bl = (const uint4*)AAfl + (size_t)t2 * 256 + l;
    f32x4 acc = {0.f, 0.f, 0.f, 0.f};
    #pragma unroll
    for (int ks = 0; ks < 4; ++ks) {
      union { uint4 u; short8v v; } BH, BL;
      BH.u = Bh[ks * 64];
      BL.u = Bl[ks * 64];
      acc = __builtin_amdgcn_mfma_f32_16x16x32_bf16(xh[ks], BH.v, acc, 0, 0, 0);
      acc = __builtin_amdgcn_mfma_f32_16x16x32_bf16(xl[ks], BH.v, acc, 0, 0, 0);
      acc = __builtin_amdgcn_mfma_f32_16x16x32_bf16(xh[ks], BL.v, acc, 0, 0, 0);
    }
    // C: col hd = t2*16+hm, row batch = mt*16 + kg*4 + r  -> scatter to Gf
    const int hd = t2 * 16 + hm;
    const int h = hd >> 7, k2 = hd & 127;
    const int base = (k2 >> 5) * 128 + h * 32 + ((k2 >> 3) & 3) * 8 + (k2 & 7);
    #pragma unroll
    for (int r = 0; r < 4; ++r) {
      size_t bb = B0 + mt * 16 + kg * 4 + r;
      float v = acc[r];
      unsigned hv = f2bf1(v);
      Gf[bb * 1024 + base] = (unsigned short)hv;
      Gf[bb * 1024 + 512 + base] =
          (unsigned short)f2bf1(v - __uint_as_float(hv << 16));
    }
  }
}

// ---------------------------------------------------------------------------
// K2: attention + out-GEMM. 512 thr / 8 batches / block, wave-per-batch.
//  - staging: two 8-deep load/process halves (latency-pipelined, regs <64)
//  - logits B-frags: direct coalesced uint4 loads from Gf (no VALU build)
//  - logits MFMA (16: 4ks x hi/lo x 2 m-tiles), softmax (2 shuffles),
//    PV on VALU from LDS, out-GEMM via CCf MFMA, bias+leaky fused
// ---------------------------------------------------------------------------
__global__ __launch_bounds__(NT) void attn_kernel(
    const float* __restrict__ nb, const unsigned short* __restrict__ Gf,
    const unsigned short* __restrict__ CCf, const float* __restrict__ bo,
    float* __restrict__ out) {

  __shared__ __align__(16) unsigned short nb16[BPB][NNB][136];  // 69632 B
  __shared__ __align__(16) unsigned ws16[BPB][260];             // 8320 B
  __shared__ __align__(16) unsigned short at16[BPB][NNB][4];    // 2048 B

  const int t = threadIdx.x;
  const size_t B0 = (size_t)blockIdx.x * BPB;
  const int wv = t >> 6, l = t & 63;
  const int hm = l & 15, kg = l >> 4;

  // ---- stage: 8 batches x 16 KB, coalesced, fp32 -> bf16; two 8-deep halves
  {
    const float4* src = (const float4*)(nb + B0 * (NNB * DD));
    float4 va[8];
    #pragma unroll
    for (int j = 0; j < 8; ++j) va[j] = src[j * NT + t];
    #pragma unroll
    for (int j = 0; j < 8; ++j) {
      int flat = j * NT + t;
      int b = flat >> 10, rem = flat & 1023;
      int n = rem >> 5, c4 = rem & 31;
      unsigned* dst = (unsigned*)&nb16[b][n][c4 * 4];
      dst[0] = pack2bf(va[j].x, va[j].y);
      dst[1] = pack2bf(va[j].z, va[j].w);
    }
    #pragma unroll
    for (int j = 0; j < 8; ++j) va[j] = src[(8 + j) * NT + t];
    #pragma unroll
    for (int j = 0; j < 8; ++j) {
      int flat = (8 + j) * NT + t;
      int b = flat >> 10, rem = flat & 1023;
      int n = rem >> 5, c4 = rem & 31;
      unsigned* dst = (unsigned*)&nb16[b][n][c4 * 4];
      dst[0] = pack2bf(va[j].x, va[j].y);
      dst[1] = pack2bf(va[j].z, va[j].w);
    }
  }

  // ---- logits B-frags: direct loads from Gf (L2-hot, frag-ordered)
  uint4 gh[4], gl[4];
  {
    const uint4* Gp = (const uint4*)Gf + (size_t)(B0 + wv) * 128 + (hm & 3) * 4 + kg;
    #pragma unroll
    for (int ks = 0; ks < 4; ++ks) {
      gh[ks] = Gp[ks * 16];
      gl[ks] = Gp[64 + ks * 16];
    }
  }
  __syncthreads();

  // ---- logits MFMA: C[n][h] over 2 m-tiles (n 0-15, 16-31), K=128
  const char* nbb = (const char*)&nb16[wv][0][0];
  f32x4 acc0 = {0.f, 0.f, 0.f, 0.f}, acc1 = {0.f, 0.f, 0.f, 0.f};
  #pragma unroll
  for (int ks = 0; ks < 4; ++ks) {
    union { uint4 u; short8v v; } A0, A1, BH, BL;
    A0.u = *(const uint4*)(nbb + hm * 272 + ks * 64 + kg * 16);
    A1.u = *(const uint4*)(nbb + (16 + hm) * 272 + ks * 64 + kg * 16);
    BH.u = gh[ks]; BL.u = gl[ks];
    acc0 = __builtin_amdgcn_mfma_f32_16x16x32_bf16(A0.v, BH.v, acc0, 0, 0, 0);
    acc0 = __builtin_amdgcn_mfma_f32_16x16x32_bf16(A0.v, BL.v, acc0, 0, 0, 0);
    acc1 = __builtin_amdgcn_mfma_f32_16x16x32_bf16(A1.v, BH.v, acc1, 0, 0, 0);
    acc1 = __builtin_amdgcn_mfma_f32_16x16x32_bf16(A1.v, BL.v, acc1, 0, 0, 0);
  }
  // ---- softmax: lane holds logits for h = hm&3 (dup), n = kg*4+r (+16)
  {
    float m = fmaxf(fmaxf(fmaxf(acc0[0], acc0[1]), fmaxf(acc0[2], acc0[3])),
                    fmaxf(fmaxf(acc1[0], acc1[1]), fmaxf(acc1[2], acc1[3])));
    m = fmaxf(m, __shfl_xor(m, 16));
    m = fmaxf(m, __shfl_xor(m, 32));
    float e0[4], e1[4], s = 0.f;
    #pragma unroll
    for (int r = 0; r < 4; ++r) {
      e0[r] = __expf(acc0[r] - m); s += e0[r];
      e1[r] = __expf(acc1[r] - m); s += e1[r];
    }
    s += __shfl_xor(s, 16);
    s += __shfl_xor(s, 32);
    float inv = 1.0f / s;
    if (hm < 4) {
      #pragma unroll
      for (int r = 0; r < 4; ++r) {
        at16[wv][kg * 4 + r][hm]      = (unsigned short)f2bf1(e0[r] * inv);
        at16[wv][16 + kg * 4 + r][hm] = (unsigned short)f2bf1(e1[r] * inv);
      }
    }
  }
  // ---- PV on VALU: lane owns cols d = 2l, 2l+1 (stride-1, conflict-free)
  {
    float w00 = 0.f, w01 = 0.f, w10 = 0.f, w11 = 0.f;
    float w20 = 0.f, w21 = 0.f, w30 = 0.f, w31 = 0.f;
    #pragma unroll 8
    for (int n = 0; n < NNB; ++n) {
      unsigned u = *(const unsigned*)(nbb + n * 272 + (l << 2));
      float f0 = bflo(u), f1 = bfhi(u);
      uint2 au = *(const uint2*)&at16[wv][n][0];   // uniform broadcast
      float a0 = bflo(au.x), a1 = bfhi(au.x);
      float a2 = bflo(au.y), a3 = bfhi(au.y);
      w00 += a0 * f0; w01 += a0 * f1;
      w10 += a1 * f0; w11 += a1 * f1;
      w20 += a2 * f0; w21 += a2 * f1;
      w30 += a3 * f0; w31 += a3 * f1;
    }
    ws16[wv][0 * 64 + l] = pack2bf(w00, w01);
    ws16[wv][1 * 64 + l] = pack2bf(w10, w11);
    ws16[wv][2 * 64 + l] = pack2bf(w20, w21);
    ws16[wv][3 * 64 + l] = pack2bf(w30, w31);
  }
  __syncthreads();

  // ---- out-GEMM: OUT[8,128] = WS[8,512] @ CC[512,128] via MFMA
  {
    const int m = hm, mb = m & 7;
    f32x4 acc = {0.f, 0.f, 0.f, 0.f};
    const uint4* Bp = (const uint4*)CCf + (size_t)wv * 1024 + l;
    #pragma unroll
    for (int s = 0; s < 16; ++s) {
      union { uint4 u; short8v v; } A, B;
      A.u = *(const uint4*)&ws16[mb][s * 16 + kg * 4];
      B.u = Bp[(size_t)s * 64];
      acc = __builtin_amdgcn_mfma_f32_16x16x32_bf16(A.v, B.v, acc, 0, 0, 0);
    }
    const int o0 = wv * 16 + m;
    float bias0 = bo[o0];
    #pragma unroll
    for (int r = 0; r < 4; ++r) {
      int bat = kg * 4 + r;
      if (bat < 8) {
        float v0 = acc[r] + bias0;
        v0 = v0 > 0.f ? v0 : 0.01f * v0;
        out[(B0 + bat) * DD + o0] = v0;
      }
    }
  }
}

// ---------------------------------------------------------------------------
extern "C" void kernel_launch(void* const* d_in, const int* in_sizes, int n_in,
                              void* d_out, int out_size, void* d_ws, size_t ws_size,
                              hipStream_t stream) {
  const float* x  = (const float*)d_in[0];
  const float* nb = (const float*)d_in[1];
  const float* Wq = (const float*)d_in[2];
  const float* Wk = (const float*)d_in[3];
  const float* Wv = (const float*)d_in[4];
  const float* Wo = (const float*)d_in[5];
  const float* bo = (const float*)d_in[6];
  float* out = (float*)d_out;

  unsigned short* W = (unsigned short*)d_ws;
  unsigned short* AAfh = W;                 // 65536 ush (128 KB)
  unsigned short* AAfl = W + 65536;         // 65536 ush
  unsigned short* CCf  = W + 131072;        // 65536 ush
  unsigned short* Gf   = W + 196608;        // 16384*1024 ush (32 MB)

  precompute_kernel<<<dim3(256, 2), 256, 0, stream>>>(Wq, Wk, Wv, Wo, AAfh, AAfl, CCf);
  gemm1_kernel<<<dim3(NBATCH / 32), 512, 0, stream>>>(x, AAfh, AAfl, Gf);
  attn_kernel<<<dim3(NBATCH / BPB), NT, 0, stream>>>(nb, Gf, CCf, bo, out);
}